// Round 9
// baseline (152.148 us; speedup 1.0000x reference)
//
#include <hip/hip_runtime.h>
#include <hip/hip_bf16.h>
#include <cstdint>
#include <cstddef>

typedef __attribute__((ext_vector_type(8))) short short8;
typedef __attribute__((ext_vector_type(4))) short short4v;
typedef __attribute__((ext_vector_type(4))) float f32x4;
typedef __attribute__((ext_vector_type(16))) float f32x16;

#define HH 12
#define DD 64
#define NN 2048
#define CC 768
// 0.125 (HEAD_DIM^-0.5) * log2(e): lets attn use exp2 directly.
#define QSCALE 0.18033688011112042f

#if defined(__has_builtin)
#if __has_builtin(__builtin_amdgcn_global_load_lds)
#define HAVE_GLOAD_LDS 1
#endif
#endif

#ifdef HAVE_GLOAD_LDS
// async global->LDS, 16B per lane; LDS dest is wave-uniform base + lane*16
#define GL16(gp, lp)                                                         \
  __builtin_amdgcn_global_load_lds(                                         \
      (__attribute__((address_space(1))) void*)(size_t)(const void*)(gp),   \
      (__attribute__((address_space(3))) void*)(lp), 16, 0, 0)
#endif

__device__ __forceinline__ float bf2f(short s) {
  union { uint32_t u; float f; } v;
  v.u = ((uint32_t)(uint16_t)s) << 16;
  return v.f;
}
__device__ __forceinline__ short f2bf(float f) {
  union { float f; uint32_t u; } v; v.f = f;
  uint32_t r = v.u + 0x7FFFu + ((v.u >> 16) & 1u);
  return (short)(r >> 16);
}
// packed f32x2 -> bf16x2 (low = a, high = b) in one instruction
__device__ __forceinline__ uint32_t cvtpk(float a, float b) {
  uint32_t r;
  asm("v_cvt_pk_bf16_f32 %0, %1, %2" : "=v"(r) : "v"(a), "v"(b));
  return r;
}

// ---------------------------------------------------------------------------
// Normalizer: fp32 -> bf16 for x, w_qkv, w_out.
// ---------------------------------------------------------------------------
__global__ __launch_bounds__(256)
void norm_k(const float* __restrict__ s0, const float* __restrict__ s1,
            const float* __restrict__ s2,
            short* __restrict__ d0, short* __restrict__ d1,
            short* __restrict__ d2)
{
  const int bid = blockIdx.x;
  const float* src; short* dst; int base;
  if (bid < 1536)      { src = s0; dst = d0; base = bid; }
  else if (bid < 2400) { src = s1; dst = d1; base = bid - 1536; }
  else                 { src = s2; dst = d2; base = bid - 2400; }
  const int idx = (base * 256 + (int)threadIdx.x) * 8;
  const float* sf = src + idx;
  f32x4 a = *(const f32x4*)sf;
  f32x4 b = *(const f32x4*)(sf + 4);
  short8 o;
  o[0] = f2bf(a[0]); o[1] = f2bf(a[1]); o[2] = f2bf(a[2]); o[3] = f2bf(a[3]);
  o[4] = f2bf(b[0]); o[5] = f2bf(b[1]); o[6] = f2bf(b[2]); o[7] = f2bf(b[3]);
  *(short8*)(dst + idx) = o;
}

// ---------------------------------------------------------------------------
// GEMM: C[m,f] = sum_c A[m,c] * W[f,c]   (A: [4096,768], W: [F,768], bf16)
// MODE 0: F=2304 -> Q (x QSCALE) [b,h,n,d], K [b,h,n,d], V^T [b,h,d,n]
// MODE 1: F=768 -> Of[m*768+f] = C + bias[f]  (fp32 out)
// Staging: global_load_lds w16, linear LDS dest, pre-swizzled global source:
//   LDS slot (row, s16) <- global (row, s16 ^ (row&7));  frag reads use the
//   same XOR, so slot ((c*4+lh)^(row&7)) returns element c*4+lh.
// ---------------------------------------------------------------------------
template <int MODE>
__global__ __launch_bounds__(256, 2)
void gemm_k(const short* __restrict__ A, const short* __restrict__ W,
            const float* __restrict__ bias,
            short* __restrict__ O0, short* __restrict__ O1, short* __restrict__ O2,
            float* __restrict__ Of)
{
  __shared__ __align__(16) short lA[128 * 64];
  __shared__ __align__(16) short lB[128 * 64];
  const int tid = threadIdx.x;
  const int w = tid >> 6, l = tid & 63;
  const int lq = l & 15, lh = l >> 4;
  const int m0 = blockIdx.y * 128;
  const int f0 = blockIdx.x * 128;

#ifdef HAVE_GLOAD_LDS
  const int lrow = l >> 3;                    // 0..7 within wave
  const int gseg = ((l & 7) ^ lrow) * 8;      // pre-swizzled element offset
#else
  const int seg = tid & 7;
  const int rbase = tid >> 3;
#endif

  f32x4 acc[4][4] = {};

  for (int kb = 0; kb < CC; kb += 64) {
    __syncthreads();
#ifdef HAVE_GLOAD_LDS
#pragma unroll
    for (int j = 0; j < 4; ++j) {
      const int rw = j * 32 + w * 8;          // wave-uniform row base
      const int row = rw + lrow;
      GL16(A + (size_t)(m0 + row) * CC + kb + gseg, &lA[rw * 64]);
      GL16(W + (size_t)(f0 + row) * CC + kb + gseg, &lB[rw * 64]);
    }
#else
#pragma unroll
    for (int j = 0; j < 4; ++j) {
      const int row = j * 32 + rbase;
      const int dst = row * 128 + ((seg * 16) ^ ((row & 7) << 4));
      *(short8*)((char*)lA + dst) =
          *(const short8*)(A + (size_t)(m0 + row) * CC + kb + seg * 8);
      *(short8*)((char*)lB + dst) =
          *(const short8*)(W + (size_t)(f0 + row) * CC + kb + seg * 8);
    }
#endif
    __syncthreads();
    const int wr = (w >> 1) * 64, wc = (w & 1) * 64;
#pragma unroll
    for (int c = 0; c < 2; ++c) {
      short8 af[4], bfr[4];
#pragma unroll
      for (int i = 0; i < 4; ++i) {
        const int rowA = wr + i * 16 + lq;
        af[i] = *(const short8*)((char*)lA + rowA * 128 +
                                 ((c * 64 + lh * 16) ^ ((rowA & 7) << 4)));
        const int rowB = wc + i * 16 + lq;
        bfr[i] = *(const short8*)((char*)lB + rowB * 128 +
                                  ((c * 64 + lh * 16) ^ ((rowB & 7) << 4)));
      }
#pragma unroll
      for (int mi = 0; mi < 4; ++mi)
#pragma unroll
        for (int ni = 0; ni < 4; ++ni)
          acc[mi][ni] = __builtin_amdgcn_mfma_f32_16x16x32_bf16(
              af[mi], bfr[ni], acc[mi][ni], 0, 0, 0);
    }
  }

  const int wr = (w >> 1) * 64, wc = (w & 1) * 64;
#pragma unroll
  for (int ni = 0; ni < 4; ++ni) {
    const int fb = f0 + wc + ni * 16;
    if (MODE == 0) {
      const int which = fb / CC;          // uniform per fragment
      const int hd = fb - which * CC;
      const int h = hd >> 6;              // uniform
      const int d = (hd & 63) + lq;
#pragma unroll
      for (int mi = 0; mi < 4; ++mi) {
        const int mb = m0 + wr + mi * 16 + 4 * lh;
        const int b = mb >> 11;
        const int n = mb & 2047;
        if (which == 0) {
#pragma unroll
          for (int r = 0; r < 4; ++r)
            O0[(((size_t)(b * HH + h) * NN) + n + r) * DD + d] =
                f2bf(acc[mi][ni][r] * QSCALE);
        } else if (which == 1) {
#pragma unroll
          for (int r = 0; r < 4; ++r)
            O1[(((size_t)(b * HH + h) * NN) + n + r) * DD + d] =
                f2bf(acc[mi][ni][r]);
        } else {
          short4v pk;
#pragma unroll
          for (int r = 0; r < 4; ++r) pk[r] = f2bf(acc[mi][ni][r]);
          *(short4v*)(O2 + ((size_t)(b * HH + h) * DD + d) * NN + n) = pk;
        }
      }
    } else {
      const float bv = bias[fb + lq];
#pragma unroll
      for (int mi = 0; mi < 4; ++mi) {
        const int mb = m0 + wr + mi * 16 + 4 * lh;
#pragma unroll
        for (int r = 0; r < 4; ++r)
          Of[(size_t)(mb + r) * CC + fb + lq] = acc[mi][ni][r] + bv;
      }
    }
  }
}

// ---------------------------------------------------------------------------
// colsumV[bh,d] = sum_n V[bh,n,d]  (from V^T [bh,d,n])
// ---------------------------------------------------------------------------
__global__ __launch_bounds__(256)
void colsum_k(const short* __restrict__ VT, float* __restrict__ cs)
{
  const int bh = blockIdx.x, t = threadIdx.x;
  const int d = t >> 2, part = t & 3;
  const short* p = VT + ((size_t)bh * DD + d) * NN + part * 512;
  float s = 0.f;
  for (int i = 0; i < 512; i += 8) {
    short8 v = *(const short8*)(p + i);
#pragma unroll
    for (int e = 0; e < 8; ++e) s += bf2f(v[e]);
  }
  s += __shfl_xor(s, 1);
  s += __shfl_xor(s, 2);
  if (part == 0) cs[bh * DD + d] = s;
}

// ---------------------------------------------------------------------------
// Attention: 768 blocks x 256 thr.  4 waves = 2 q-subtiles x 2 k-chunks.
// T14 async-STAGE split: next tile's global loads issue BEFORE compute
// (latency hides under QK/exp/PV); ds_write lands after the read barrier.
// Intra-block split-K combine via LDS overlay.  32x32x16 MFMA, swapped QK^T,
// P->A-frag via v_permlane32_swap_b32.  Linearized 2nd softmax:
//   out = (csV*l1 + P1) / (2048*l1 + s1),  s1 = l1 - 0.5*mc.
// ---------------------------------------------------------------------------
__global__ __launch_bounds__(256, 3)
void attn_k(const short* __restrict__ Qb, const short* __restrict__ Kb,
            const short* __restrict__ VT, const float* __restrict__ cs,
            short* __restrict__ AO)
{
  __shared__ __align__(16) char smem[32768];   // staging; combine overlay
  float* comb  = (float*)smem;                 // [64 q][64 d] fp32
  float* combL = comb + 4096;                  // l1 partials [64]
  float* combM = comb + 4160;                  // mc partials [64]

  const int tid = threadIdx.x;
  const int w = tid >> 6, l = tid & 63;
  const int lq = l & 31, hi = l >> 5;
  const int qp = w & 1;                        // q subtile (0: q0-31, 1: q32-63)
  const int kc = w >> 1;                       // k chunk   (0: k<1024, 1: k>=1024)

  // XCD-aware chunked swizzle: 768 % 8 == 0, bijective.
  const int bid = (int)blockIdx.x;
  const int sbid = (bid & 7) * 96 + (bid >> 3);
  const int bh = sbid >> 5;
  const int qblk = sbid & 31;

  const short* Qh = Qb + (size_t)bh * NN * DD;
  const short* Kh = Kb + (size_t)bh * NN * DD;
  const short* Vh = VT + (size_t)bh * DD * NN;

  const int qw = qblk * 64 + qp * 32;
  const int qg = qw + lq;

  // B-frag of Q: rows d = c*16 + hi*8 + 0..7, col q = lq
  short8 qf[4];
#pragma unroll
  for (int c = 0; c < 4; ++c)
    qf[c] = *(const short8*)(Qh + (size_t)qg * DD + c * 16 + hi * 8);

  f32x16 pv[2] = {};
  float l1x[4] = {};
  float mc = 0.f;

  // staging: the 128 threads of each k-chunk pair stage their own tile
  const int lt = tid & 127;
  const int seg = lt & 7, rbase = lt >> 3;     // 8 segs x 16 rows
  const int cbase = kc * 16384;                // this chunk's staging base (bytes)
  int sdstK[4], sdstV[4], ksrc[4], vsrc[4];
#pragma unroll
  for (int j = 0; j < 4; ++j) {
    const int row = j * 16 + rbase;
    const int sw = row * 128 + ((seg * 16) ^ ((row & 7) << 4));
    sdstK[j] = cbase + sw;
    sdstV[j] = cbase + 8192 + sw;
    ksrc[j] = row * DD + seg * 8;
    vsrc[j] = row * NN + seg * 8;
  }
  // hoisted LDS frag-read addresses (loop-invariant)
  int kaddr[8], vaddr[8];
#pragma unroll
  for (int kg = 0; kg < 2; ++kg) {
    const int rowK = kg * 32 + lq;
#pragma unroll
    for (int c = 0; c < 4; ++c)
      kaddr[kg * 4 + c] =
          cbase + rowK * 128 + ((c * 32 + hi * 16) ^ ((rowK & 7) << 4));
  }
#pragma unroll
  for (int dg = 0; dg < 2; ++dg) {
    const int rowV = dg * 32 + lq;
#pragma unroll
    for (int ch = 0; ch < 4; ++ch)
      vaddr[ch * 2 + dg] =
          cbase + 8192 + rowV * 128 + ((ch * 32 + hi * 16) ^ ((rowV & 7) << 4));
  }

  const int kb0 = kc * (NN / 2);

  // T14 stage registers
  short8 kreg[4], vreg[4];
#pragma unroll
  for (int j = 0; j < 4; ++j) {
    kreg[j] = *(const short8*)(Kh + (size_t)kb0 * DD + ksrc[j]);
    vreg[j] = *(const short8*)(Vh + kb0 + vsrc[j]);
  }
#pragma unroll
  for (int j = 0; j < 4; ++j) {
    *(short8*)(smem + sdstK[j]) = kreg[j];
    *(short8*)(smem + sdstV[j]) = vreg[j];
  }

  for (int t = 0; t < NN / 2; t += 64) {
    const int kb = kb0 + t;
    __syncthreads();                         // tile t visible in LDS
    if (t + 64 < NN / 2) {                   // issue next-tile loads (async)
#pragma unroll
      for (int j = 0; j < 4; ++j) {
        kreg[j] = *(const short8*)(Kh + (size_t)(kb + 64) * DD + ksrc[j]);
        vreg[j] = *(const short8*)(Vh + kb + 64 + vsrc[j]);
      }
    }

    // QK^T: sacc[kg] = S[key = kb + kg*32 + crow, q = qg] * log2e
    // crow = (reg&3) + 8*(reg>>2) + 4*hi
    f32x16 sacc[2] = {};
    __builtin_amdgcn_s_setprio(1);
#pragma unroll
    for (int kg = 0; kg < 2; ++kg)
#pragma unroll
      for (int c = 0; c < 4; ++c) {
        short8 kf = *(const short8*)(smem + kaddr[kg * 4 + c]);
        sacc[kg] = __builtin_amdgcn_mfma_f32_32x32x16_bf16(kf, qf[c], sacc[kg], 0, 0, 0);
      }
    __builtin_amdgcn_s_setprio(0);

    // elementwise: e = exp2(s); mask hoisted to rare wave-uniform tiles
    uint32_t dwv[2][8];
    const int u = (qw - kb) & 511;
    if (u < 64 || u > 480) {
      const int delta = (qg - kb) & 511;
      int mreg = -1;
      if (delta < 64 && (((delta >> 2) & 1) == hi))
        mreg = (delta >> 5) * 16 + (delta & 3) + (((delta & 31) >> 3) << 2);
#pragma unroll
      for (int kg = 0; kg < 2; ++kg) {
        float uv[16];
#pragma unroll
        for (int r = 0; r < 16; ++r) {
          float e = __builtin_exp2f(sacc[kg][r]);
          l1x[r & 3] += e;
          const bool m = (kg * 16 + r) == mreg;
          mc += m ? e : 0.f;
          uv[r] = m ? 0.5f * e : e;
        }
#pragma unroll
        for (int j2 = 0; j2 < 8; ++j2)
          dwv[kg][j2] = cvtpk(uv[2 * j2], uv[2 * j2 + 1]);
      }
    } else {
#pragma unroll
      for (int kg = 0; kg < 2; ++kg) {
        float uv[16];
#pragma unroll
        for (int r = 0; r < 16; ++r) {
          const float e = __builtin_exp2f(sacc[kg][r]);
          l1x[r & 3] += e;
          uv[r] = e;
        }
#pragma unroll
        for (int j2 = 0; j2 < 8; ++j2)
          dwv[kg][j2] = cvtpk(uv[2 * j2], uv[2 * j2 + 1]);
      }
    }

    // Build PV A-frags (P[q][k], row=q=lq, cols k = ch*16 + hi*8 + 0..7)
    short8 pa[4];
#pragma unroll
    for (int kg = 0; kg < 2; ++kg)
#pragma unroll
      for (int half = 0; half < 2; ++half) {
        uint32_t a0 = dwv[kg][4 * half + 0], a1 = dwv[kg][4 * half + 1];
        uint32_t a2 = dwv[kg][4 * half + 2], a3 = dwv[kg][4 * half + 3];
        asm("v_permlane32_swap_b32 %0, %1" : "+v"(a0), "+v"(a2));
        asm("v_permlane32_swap_b32 %0, %1" : "+v"(a1), "+v"(a3));
        union { uint32_t u4[4]; short8 s; } pk;
        pk.u4[0] = a0; pk.u4[1] = a1; pk.u4[2] = a2; pk.u4[3] = a3;
        pa[kg * 2 + half] = pk.s;
      }

    // PV: pv[dg][reg] = O[q = crow, d = dg*32 + lq]
    __builtin_amdgcn_s_setprio(1);
#pragma unroll
    for (int ch = 0; ch < 4; ++ch)
#pragma unroll
      for (int dg = 0; dg < 2; ++dg) {
        short8 vf = *(const short8*)(smem + vaddr[ch * 2 + dg]);
        pv[dg] = __builtin_amdgcn_mfma_f32_32x32x16_bf16(pa[ch], vf, pv[dg], 0, 0, 0);
      }
    __builtin_amdgcn_s_setprio(0);

    __syncthreads();                         // all reads of tile t done
    if (t + 64 < NN / 2) {                   // land next tile in LDS
#pragma unroll
      for (int j = 0; j < 4; ++j) {
        *(short8*)(smem + sdstK[j]) = kreg[j];
        *(short8*)(smem + sdstV[j]) = vreg[j];
      }
    }
  }

  // per-chunk l1, mc for q = qw + lq (keys split across lane halves)
  float l1 = (l1x[0] + l1x[1]) + (l1x[2] + l1x[3]);
  l1 += __shfl_xor(l1, 32);
  mc += __shfl_xor(mc, 32);

  // ---- intra-block split-K combine via LDS overlay ----
  __syncthreads();                    // all staging traffic done; safe to overlay
  if (kc == 1) {
#pragma unroll
    for (int dg = 0; dg < 2; ++dg)
#pragma unroll
      for (int r = 0; r < 16; ++r) {
        const int qrow = (r & 3) + 8 * (r >> 2) + 4 * hi;
        comb[(qp * 32 + qrow) * 64 + dg * 32 + lq] = pv[dg][r];
      }
    if (hi == 0) {
      combL[qp * 32 + lq] = l1;
      combM[qp * 32 + lq] = mc;
    }
  }
  __syncthreads();
  if (kc == 0) {
    const float l1t = l1 + combL[qp * 32 + lq];
    const float mct = mc + combM[qp * 32 + lq];
    const float s1t = l1t - 0.5f * mct;
    const int b = bh / HH, h = bh - b * HH;
#pragma unroll
    for (int r = 0; r < 16; ++r) {
      const int qrow = (r & 3) + 8 * (r >> 2) + 4 * hi;
      const float l1r = __shfl(l1t, qrow);
      const float s1r = __shfl(s1t, qrow);
      const float rden = 1.f / (2048.f * l1r + s1r);
      const int n = qw + qrow;
#pragma unroll
      for (int dg = 0; dg < 2; ++dg) {
        const int d = dg * 32 + lq;
        const float pvt = pv[dg][r] + comb[(qp * 32 + qrow) * 64 + d];
        const float csv = cs[bh * DD + d];
        AO[((size_t)(b * NN + n)) * CC + h * DD + d] =
            f2bf((csv * l1r + pvt) * rden);
      }
    }
  }
}

// ---------------------------------------------------------------------------
extern "C" void kernel_launch(void* const* d_in, const int* in_sizes, int n_in,
                              void* d_out, int out_size, void* d_ws, size_t ws_size,
                              hipStream_t stream)
{
  (void)in_sizes; (void)n_in; (void)out_size;
  float* out = (float*)d_out;

  const size_t HD = (size_t)2 * HH * NN * DD;   // 3,145,728 elements
  const size_t NX = 3145728, NW = 1769472, NO = 589824;
  const size_t need = (4 * HD + NX + NW + NO) * sizeof(short)
                    + (size_t)2 * HH * DD * sizeof(float) + 64;
  if (ws_size < need) return;  // diagnostic: zero output

  short* Qb = (short*)d_ws;
  short* Kb = Qb + HD;
  short* VT = Kb + HD;
  short* AO = VT + HD;
  float* cs = (float*)(AO + HD);
  short* xb  = (short*)(cs + 2 * HH * DD);
  short* wqb = xb + NX;
  short* wob = wqb + NW;

  dim3 blk(256);
  norm_k<<<dim3(2688), blk, 0, stream>>>((const float*)d_in[0],
                                         (const float*)d_in[1],
                                         (const float*)d_in[2],
                                         xb, wqb, wob);
  gemm_k<0><<<dim3(2304 / 128, 4096 / 128), blk, 0, stream>>>(
      xb, wqb, nullptr, Qb, Kb, VT, nullptr);
  colsum_k<<<dim3(2 * HH), blk, 0, stream>>>(VT, cs);
  attn_k<<<dim3(24 * 32), blk, 0, stream>>>(Qb, Kb, VT, cs, AO);
  gemm_k<1><<<dim3(CC / 128, 4096 / 128), blk, 0, stream>>>(
      AO, wob, (const float*)d_in[3], nullptr, nullptr, nullptr, out);
}

// Round 10
// 151.290 us; speedup vs baseline: 1.0057x; 1.0057x over previous
//
#include <hip/hip_runtime.h>
#include <hip/hip_bf16.h>
#include <cstdint>
#include <cstddef>

typedef __attribute__((ext_vector_type(8))) short short8;
typedef __attribute__((ext_vector_type(4))) short short4v;
typedef __attribute__((ext_vector_type(4))) float f32x4;
typedef __attribute__((ext_vector_type(16))) float f32x16;

#define HH 12
#define DD 64
#define NN 2048
#define CC 768
// 0.125 (HEAD_DIM^-0.5) * log2(e): lets attn use exp2 directly.
#define QSCALE 0.18033688011112042f

#if defined(__has_builtin)
#if __has_builtin(__builtin_amdgcn_global_load_lds)
#define HAVE_GLOAD_LDS 1
#endif
#endif

#ifdef HAVE_GLOAD_LDS
// async global->LDS, 16B per lane; LDS dest is wave-uniform base + lane*16
#define GL16(gp, lp)                                                         \
  __builtin_amdgcn_global_load_lds(                                         \
      (__attribute__((address_space(1))) void*)(size_t)(const void*)(gp),   \
      (__attribute__((address_space(3))) void*)(lp), 16, 0, 0)
#endif

__device__ __forceinline__ float bf2f(short s) {
  union { uint32_t u; float f; } v;
  v.u = ((uint32_t)(uint16_t)s) << 16;
  return v.f;
}
__device__ __forceinline__ short f2bf(float f) {
  union { float f; uint32_t u; } v; v.f = f;
  uint32_t r = v.u + 0x7FFFu + ((v.u >> 16) & 1u);
  return (short)(r >> 16);
}
// packed f32x2 -> bf16x2 (low = a, high = b) in one instruction
__device__ __forceinline__ uint32_t cvtpk(float a, float b) {
  uint32_t r;
  asm("v_cvt_pk_bf16_f32 %0, %1, %2" : "=v"(r) : "v"(a), "v"(b));
  return r;
}

// ---------------------------------------------------------------------------
// Normalizer: fp32 -> bf16 for x, w_qkv, w_out.
// ---------------------------------------------------------------------------
__global__ __launch_bounds__(256)
void norm_k(const float* __restrict__ s0, const float* __restrict__ s1,
            const float* __restrict__ s2,
            short* __restrict__ d0, short* __restrict__ d1,
            short* __restrict__ d2)
{
  const int bid = blockIdx.x;
  const float* src; short* dst; int base;
  if (bid < 1536)      { src = s0; dst = d0; base = bid; }
  else if (bid < 2400) { src = s1; dst = d1; base = bid - 1536; }
  else                 { src = s2; dst = d2; base = bid - 2400; }
  const int idx = (base * 256 + (int)threadIdx.x) * 8;
  const float* sf = src + idx;
  f32x4 a = *(const f32x4*)sf;
  f32x4 b = *(const f32x4*)(sf + 4);
  short8 o;
  o[0] = f2bf(a[0]); o[1] = f2bf(a[1]); o[2] = f2bf(a[2]); o[3] = f2bf(a[3]);
  o[4] = f2bf(b[0]); o[5] = f2bf(b[1]); o[6] = f2bf(b[2]); o[7] = f2bf(b[3]);
  *(short8*)(dst + idx) = o;
}

// ---------------------------------------------------------------------------
// GEMM: C[m,f] = sum_c A[m,c] * W[f,c]   (A: [4096,768], W: [F,768], bf16)
// MODE 0: F=2304 -> Q (x QSCALE) [b,h,n,d], K [b,h,n,d], V^T [b,h,d,n]
// MODE 1: F=768 -> Of[m*768+f] = C + bias[f]  (fp32 out)
// Staging: global_load_lds w16, linear LDS dest, pre-swizzled global source.
// ---------------------------------------------------------------------------
template <int MODE>
__global__ __launch_bounds__(256, 2)
void gemm_k(const short* __restrict__ A, const short* __restrict__ W,
            const float* __restrict__ bias,
            short* __restrict__ O0, short* __restrict__ O1, short* __restrict__ O2,
            float* __restrict__ Of)
{
  __shared__ __align__(16) short lA[128 * 64];
  __shared__ __align__(16) short lB[128 * 64];
  const int tid = threadIdx.x;
  const int w = tid >> 6, l = tid & 63;
  const int lq = l & 15, lh = l >> 4;
  const int m0 = blockIdx.y * 128;
  const int f0 = blockIdx.x * 128;

#ifdef HAVE_GLOAD_LDS
  const int lrow = l >> 3;                    // 0..7 within wave
  const int gseg = ((l & 7) ^ lrow) * 8;      // pre-swizzled element offset
#else
  const int seg = tid & 7;
  const int rbase = tid >> 3;
#endif

  f32x4 acc[4][4] = {};

  for (int kb = 0; kb < CC; kb += 64) {
    __syncthreads();
#ifdef HAVE_GLOAD_LDS
#pragma unroll
    for (int j = 0; j < 4; ++j) {
      const int rw = j * 32 + w * 8;          // wave-uniform row base
      const int row = rw + lrow;
      GL16(A + (size_t)(m0 + row) * CC + kb + gseg, &lA[rw * 64]);
      GL16(W + (size_t)(f0 + row) * CC + kb + gseg, &lB[rw * 64]);
    }
#else
#pragma unroll
    for (int j = 0; j < 4; ++j) {
      const int row = j * 32 + rbase;
      const int dst = row * 128 + ((seg * 16) ^ ((row & 7) << 4));
      *(short8*)((char*)lA + dst) =
          *(const short8*)(A + (size_t)(m0 + row) * CC + kb + seg * 8);
      *(short8*)((char*)lB + dst) =
          *(const short8*)(W + (size_t)(f0 + row) * CC + kb + seg * 8);
    }
#endif
    __syncthreads();
    const int wr = (w >> 1) * 64, wc = (w & 1) * 64;
#pragma unroll
    for (int c = 0; c < 2; ++c) {
      short8 af[4], bfr[4];
#pragma unroll
      for (int i = 0; i < 4; ++i) {
        const int rowA = wr + i * 16 + lq;
        af[i] = *(const short8*)((char*)lA + rowA * 128 +
                                 ((c * 64 + lh * 16) ^ ((rowA & 7) << 4)));
        const int rowB = wc + i * 16 + lq;
        bfr[i] = *(const short8*)((char*)lB + rowB * 128 +
                                  ((c * 64 + lh * 16) ^ ((rowB & 7) << 4)));
      }
#pragma unroll
      for (int mi = 0; mi < 4; ++mi)
#pragma unroll
        for (int ni = 0; ni < 4; ++ni)
          acc[mi][ni] = __builtin_amdgcn_mfma_f32_16x16x32_bf16(
              af[mi], bfr[ni], acc[mi][ni], 0, 0, 0);
    }
  }

  const int wr = (w >> 1) * 64, wc = (w & 1) * 64;
#pragma unroll
  for (int ni = 0; ni < 4; ++ni) {
    const int fb = f0 + wc + ni * 16;
    if (MODE == 0) {
      const int which = fb / CC;          // uniform per fragment
      const int hd = fb - which * CC;
      const int h = hd >> 6;              // uniform
      const int d = (hd & 63) + lq;
#pragma unroll
      for (int mi = 0; mi < 4; ++mi) {
        const int mb = m0 + wr + mi * 16 + 4 * lh;
        const int b = mb >> 11;
        const int n = mb & 2047;
        if (which == 0) {
#pragma unroll
          for (int r = 0; r < 4; ++r)
            O0[(((size_t)(b * HH + h) * NN) + n + r) * DD + d] =
                f2bf(acc[mi][ni][r] * QSCALE);
        } else if (which == 1) {
#pragma unroll
          for (int r = 0; r < 4; ++r)
            O1[(((size_t)(b * HH + h) * NN) + n + r) * DD + d] =
                f2bf(acc[mi][ni][r]);
        } else {
          short4v pk;
#pragma unroll
          for (int r = 0; r < 4; ++r) pk[r] = f2bf(acc[mi][ni][r]);
          *(short4v*)(O2 + ((size_t)(b * HH + h) * DD + d) * NN + n) = pk;
        }
      }
    } else {
      const float bv = bias[fb + lq];
#pragma unroll
      for (int mi = 0; mi < 4; ++mi) {
        const int mb = m0 + wr + mi * 16 + 4 * lh;
#pragma unroll
        for (int r = 0; r < 4; ++r)
          Of[(size_t)(mb + r) * CC + fb + lq] = acc[mi][ni][r] + bv;
      }
    }
  }
}

// ---------------------------------------------------------------------------
// colsumV[bh,d] = sum_n V[bh,n,d]  (from V^T [bh,d,n])
// ---------------------------------------------------------------------------
__global__ __launch_bounds__(256)
void colsum_k(const short* __restrict__ VT, float* __restrict__ cs)
{
  const int bh = blockIdx.x, t = threadIdx.x;
  const int d = t >> 2, part = t & 3;
  const short* p = VT + ((size_t)bh * DD + d) * NN + part * 512;
  float s = 0.f;
  for (int i = 0; i < 512; i += 8) {
    short8 v = *(const short8*)(p + i);
#pragma unroll
    for (int e = 0; e < 8; ++e) s += bf2f(v[e]);
  }
  s += __shfl_xor(s, 1);
  s += __shfl_xor(s, 2);
  if (part == 0) cs[bh * DD + d] = s;
}

// ---------------------------------------------------------------------------
// Attention, stage-free: 1536 blocks x 256 thr.  4 waves = 4 k-chunks (512
// keys each) over the SAME 32 queries.  K/V^T fragments read DIRECTLY from
// global (L2-resident; no per-wave tile reuse -> LDS staging is pure
// overhead).  NO barriers in the K-loop; waves fully independent.  LDS only
// for the final 4-way split-K combine (25.3 KB).  32x32x16 MFMA, swapped
// QK^T (lane owns q=lane&31); P->A-frag via v_permlane32_swap_b32.
// Linearized 2nd softmax: out = (csV*l1 + P1)/(2048*l1 + s1), s1 = l1-0.5*mc.
// ---------------------------------------------------------------------------
__global__ __launch_bounds__(256, 4)
void attn_k(const short* __restrict__ Qb, const short* __restrict__ Kb,
            const short* __restrict__ VT, const float* __restrict__ cs,
            short* __restrict__ AO)
{
  __shared__ float comb[3 * 2112];             // 3 partial records: pv|l1|mc

  const int tid = threadIdx.x;
  const int kc = tid >> 6, l = tid & 63;       // wave = k-chunk
  const int lq = l & 31, hi = l >> 5;

  // XCD-aware chunked swizzle: 1536 % 8 == 0, bijective.
  const int bid = (int)blockIdx.x;
  const int sbid = (bid & 7) * 192 + (bid >> 3);
  const int bh = sbid >> 6;
  const int qblk = sbid & 63;

  const short* Qh = Qb + (size_t)bh * NN * DD;
  const short* Kh = Kb + (size_t)bh * NN * DD;
  const short* Vh = VT + (size_t)bh * DD * NN;

  const int qw = qblk * 32;
  const int qg = qw + lq;

  // B-frag of Q: rows d = c*16 + hi*8 + 0..7, col q = lq
  short8 qf[4];
#pragma unroll
  for (int c = 0; c < 4; ++c)
    qf[c] = *(const short8*)(Qh + (size_t)qg * DD + c * 16 + hi * 8);

  f32x16 pv[2] = {};
  float l1x[4] = {};
  float mc = 0.f;

  const int kb0 = kc * (NN / 4);
  // per-lane global frag pointers (advance per tile)
  const short* kp0 = Kh + (size_t)(kb0 + lq) * DD + hi * 8;        // kg=0 rows
  const short* kp1 = Kh + (size_t)(kb0 + 32 + lq) * DD + hi * 8;   // kg=1 rows
  const short* vp0 = Vh + (size_t)lq * NN + kb0 + hi * 8;          // dg=0 rows
  const short* vp1 = Vh + (size_t)(32 + lq) * NN + kb0 + hi * 8;   // dg=1 rows

  for (int t = 0; t < NN / 4; t += 64) {
    const int kb = kb0 + t;
    short8 pa[4];

    // ---- QK^T + exp + pack, one kg (32-key group) at a time ----
    const int u = (qw - kb) & 511;
    const bool tile_masked = (u < 64 || u > 480);
    const int delta = (qg - kb) & 511;
#pragma unroll
    for (int kg = 0; kg < 2; ++kg) {
      const short* kp = kg ? kp1 : kp0;
      f32x16 sacc = {};
      __builtin_amdgcn_s_setprio(1);
#pragma unroll
      for (int c = 0; c < 4; ++c) {
        short8 kf = *(const short8*)(kp + c * 16);
        sacc = __builtin_amdgcn_mfma_f32_32x32x16_bf16(kf, qf[c], sacc, 0, 0, 0);
      }
      __builtin_amdgcn_s_setprio(0);

      uint32_t dw[8];
      if (tile_masked) {
        int mreg = -1;
        if (delta < 64 && (delta >> 5) == kg && ((delta >> 2) & 1) == hi)
          mreg = (delta & 3) + (((delta & 31) >> 3) << 2);
        float uv[16];
#pragma unroll
        for (int r = 0; r < 16; ++r) {
          float e = __builtin_exp2f(sacc[r]);
          l1x[r & 3] += e;
          const bool m = (r == mreg);
          mc += m ? e : 0.f;
          uv[r] = m ? 0.5f * e : e;
        }
#pragma unroll
        for (int j2 = 0; j2 < 8; ++j2)
          dw[j2] = cvtpk(uv[2 * j2], uv[2 * j2 + 1]);
      } else {
        float uv[16];
#pragma unroll
        for (int r = 0; r < 16; ++r) {
          const float e = __builtin_exp2f(sacc[r]);
          l1x[r & 3] += e;
          uv[r] = e;
        }
#pragma unroll
        for (int j2 = 0; j2 < 8; ++j2)
          dw[j2] = cvtpk(uv[2 * j2], uv[2 * j2 + 1]);
      }

      // P->A-frag (P[q][k], row=q=lq, cols k = (kg*2+half)*16 + hi*8 + 0..7)
#pragma unroll
      for (int half = 0; half < 2; ++half) {
        uint32_t a0 = dw[4 * half + 0], a1 = dw[4 * half + 1];
        uint32_t a2 = dw[4 * half + 2], a3 = dw[4 * half + 3];
        asm("v_permlane32_swap_b32 %0, %1" : "+v"(a0), "+v"(a2));
        asm("v_permlane32_swap_b32 %0, %1" : "+v"(a1), "+v"(a3));
        union { uint32_t u4[4]; short8 s; } pk;
        pk.u4[0] = a0; pk.u4[1] = a1; pk.u4[2] = a2; pk.u4[3] = a3;
        pa[kg * 2 + half] = pk.s;
      }
    }

    // ---- PV: pv[dg][reg] = O[q = crow, d = dg*32 + lq] ----
    __builtin_amdgcn_s_setprio(1);
#pragma unroll
    for (int ch = 0; ch < 4; ++ch) {
      short8 vf0 = *(const short8*)(vp0 + t + ch * 16);
      short8 vf1 = *(const short8*)(vp1 + t + ch * 16);
      pv[0] = __builtin_amdgcn_mfma_f32_32x32x16_bf16(pa[ch], vf0, pv[0], 0, 0, 0);
      pv[1] = __builtin_amdgcn_mfma_f32_32x32x16_bf16(pa[ch], vf1, pv[1], 0, 0, 0);
    }
    __builtin_amdgcn_s_setprio(0);

    kp0 += 64 * DD;
    kp1 += 64 * DD;
  }

  // per-chunk l1, mc for q = qg (keys split across lane halves)
  float l1 = (l1x[0] + l1x[1]) + (l1x[2] + l1x[3]);
  l1 += __shfl_xor(l1, 32);
  mc += __shfl_xor(mc, 32);

  // ---- 4-way split-K combine via LDS ----
  if (kc) {
    float* pb = comb + (kc - 1) * 2112;
#pragma unroll
    for (int dg = 0; dg < 2; ++dg)
#pragma unroll
      for (int r = 0; r < 16; ++r) {
        const int qrow = (r & 3) + 8 * (r >> 2) + 4 * hi;
        pb[qrow * 64 + dg * 32 + lq] = pv[dg][r];
      }
    if (hi == 0) {
      pb[2048 + lq] = l1;
      pb[2080 + lq] = mc;
    }
  }
  __syncthreads();
  if (kc == 0) {
    const float l1t = l1 + comb[2048 + lq] + comb[2112 + 2048 + lq] +
                      comb[2 * 2112 + 2048 + lq];
    const float mct = mc + comb[2080 + lq] + comb[2112 + 2080 + lq] +
                      comb[2 * 2112 + 2080 + lq];
    const float s1t = l1t - 0.5f * mct;
    const int b = bh / HH, h = bh - b * HH;
#pragma unroll
    for (int r = 0; r < 16; ++r) {
      const int qrow = (r & 3) + 8 * (r >> 2) + 4 * hi;
      const float l1r = __shfl(l1t, qrow);
      const float s1r = __shfl(s1t, qrow);
      const float rden = 1.f / (2048.f * l1r + s1r);
      const int n = qw + qrow;
#pragma unroll
      for (int dg = 0; dg < 2; ++dg) {
        const int d = dg * 32 + lq;
        const float pvt = pv[dg][r] + comb[qrow * 64 + d] +
                          comb[2112 + qrow * 64 + d] +
                          comb[2 * 2112 + qrow * 64 + d];
        const float csv = cs[bh * DD + d];
        AO[((size_t)(b * NN + n)) * CC + h * DD + d] =
            f2bf((csv * l1r + pvt) * rden);
      }
    }
  }
}

// ---------------------------------------------------------------------------
extern "C" void kernel_launch(void* const* d_in, const int* in_sizes, int n_in,
                              void* d_out, int out_size, void* d_ws, size_t ws_size,
                              hipStream_t stream)
{
  (void)in_sizes; (void)n_in; (void)out_size;
  float* out = (float*)d_out;

  const size_t HD = (size_t)2 * HH * NN * DD;   // 3,145,728 elements
  const size_t NX = 3145728, NW = 1769472, NO = 589824;
  const size_t need = (4 * HD + NX + NW + NO) * sizeof(short)
                    + (size_t)2 * HH * DD * sizeof(float) + 64;
  if (ws_size < need) return;  // diagnostic: zero output

  short* Qb = (short*)d_ws;
  short* Kb = Qb + HD;
  short* VT = Kb + HD;
  short* AO = VT + HD;
  float* cs = (float*)(AO + HD);
  short* xb  = (short*)(cs + 2 * HH * DD);
  short* wqb = xb + NX;
  short* wob = wqb + NW;

  dim3 blk(256);
  norm_k<<<dim3(2688), blk, 0, stream>>>((const float*)d_in[0],
                                         (const float*)d_in[1],
                                         (const float*)d_in[2],
                                         xb, wqb, wob);
  gemm_k<0><<<dim3(2304 / 128, 4096 / 128), blk, 0, stream>>>(
      xb, wqb, nullptr, Qb, Kb, VT, nullptr);
  colsum_k<<<dim3(2 * HH), blk, 0, stream>>>(VT, cs);
  attn_k<<<dim3(24 * 64), blk, 0, stream>>>(Qb, Kb, VT, cs, AO);
  gemm_k<1><<<dim3(CC / 128, 4096 / 128), blk, 0, stream>>>(
      AO, wob, (const float*)d_in[3], nullptr, nullptr, nullptr, out);
}

// Round 11
// 110.827 us; speedup vs baseline: 1.3729x; 1.3651x over previous
//
#include <hip/hip_runtime.h>
#include <hip/hip_bf16.h>
#include <cstdint>
#include <cstddef>

typedef __attribute__((ext_vector_type(8))) short short8;
typedef __attribute__((ext_vector_type(4))) short short4v;
typedef __attribute__((ext_vector_type(4))) float f32x4;
typedef __attribute__((ext_vector_type(16))) float f32x16;

#define HH 12
#define DD 64
#define NN 2048
#define CC 768
// 0.125 (HEAD_DIM^-0.5) * log2(e): lets attn use exp2 directly.
#define QSCALE 0.18033688011112042f

#if defined(__has_builtin)
#if __has_builtin(__builtin_amdgcn_global_load_lds)
#define HAVE_GLOAD_LDS 1
#endif
#endif

#ifdef HAVE_GLOAD_LDS
// async global->LDS, 16B per lane; LDS dest is wave-uniform base + lane*16
#define GL16(gp, lp)                                                         \
  __builtin_amdgcn_global_load_lds(                                         \
      (__attribute__((address_space(1))) void*)(size_t)(const void*)(gp),   \
      (__attribute__((address_space(3))) void*)(lp), 16, 0, 0)
#endif

__device__ __forceinline__ float bf2f(short s) {
  union { uint32_t u; float f; } v;
  v.u = ((uint32_t)(uint16_t)s) << 16;
  return v.f;
}
__device__ __forceinline__ short f2bf(float f) {
  union { float f; uint32_t u; } v; v.f = f;
  uint32_t r = v.u + 0x7FFFu + ((v.u >> 16) & 1u);
  return (short)(r >> 16);
}
// packed f32x2 -> bf16x2 (low = a, high = b) in one instruction
__device__ __forceinline__ uint32_t cvtpk(float a, float b) {
  uint32_t r;
  asm("v_cvt_pk_bf16_f32 %0, %1, %2" : "=v"(r) : "v"(a), "v"(b));
  return r;
}

// ---------------------------------------------------------------------------
// Normalizer: fp32 -> bf16 for x, w_qkv, w_out.
// ---------------------------------------------------------------------------
__global__ __launch_bounds__(256)
void norm_k(const float* __restrict__ s0, const float* __restrict__ s1,
            const float* __restrict__ s2,
            short* __restrict__ d0, short* __restrict__ d1,
            short* __restrict__ d2)
{
  const int bid = blockIdx.x;
  const float* src; short* dst; int base;
  if (bid < 1536)      { src = s0; dst = d0; base = bid; }
  else if (bid < 2400) { src = s1; dst = d1; base = bid - 1536; }
  else                 { src = s2; dst = d2; base = bid - 2400; }
  const int idx = (base * 256 + (int)threadIdx.x) * 8;
  const float* sf = src + idx;
  f32x4 a = *(const f32x4*)sf;
  f32x4 b = *(const f32x4*)(sf + 4);
  short8 o;
  o[0] = f2bf(a[0]); o[1] = f2bf(a[1]); o[2] = f2bf(a[2]); o[3] = f2bf(a[3]);
  o[4] = f2bf(b[0]); o[5] = f2bf(b[1]); o[6] = f2bf(b[2]); o[7] = f2bf(b[3]);
  *(short8*)(dst + idx) = o;
}

// ---------------------------------------------------------------------------
// GEMM: C[m,f] = sum_c A[m,c] * W[f,c]   (A: [4096,768], W: [F,768], bf16)
// MODE 0: F=2304 -> Q (x QSCALE) [b,h,n,d], K [b,h,n,d], V^T [b,h,d,n]
// MODE 1: F=768 -> Of[m*768+f] = C + bias[f]  (fp32 out)
// Staging: global_load_lds w16, linear LDS dest, pre-swizzled global source.
// ---------------------------------------------------------------------------
template <int MODE>
__global__ __launch_bounds__(256, 2)
void gemm_k(const short* __restrict__ A, const short* __restrict__ W,
            const float* __restrict__ bias,
            short* __restrict__ O0, short* __restrict__ O1, short* __restrict__ O2,
            float* __restrict__ Of)
{
  __shared__ __align__(16) short lA[128 * 64];
  __shared__ __align__(16) short lB[128 * 64];
  const int tid = threadIdx.x;
  const int w = tid >> 6, l = tid & 63;
  const int lq = l & 15, lh = l >> 4;
  const int m0 = blockIdx.y * 128;
  const int f0 = blockIdx.x * 128;

#ifdef HAVE_GLOAD_LDS
  const int lrow = l >> 3;                    // 0..7 within wave
  const int gseg = ((l & 7) ^ lrow) * 8;      // pre-swizzled element offset
#else
  const int seg = tid & 7;
  const int rbase = tid >> 3;
#endif

  f32x4 acc[4][4] = {};

  for (int kb = 0; kb < CC; kb += 64) {
    __syncthreads();
#ifdef HAVE_GLOAD_LDS
#pragma unroll
    for (int j = 0; j < 4; ++j) {
      const int rw = j * 32 + w * 8;          // wave-uniform row base
      const int row = rw + lrow;
      GL16(A + (size_t)(m0 + row) * CC + kb + gseg, &lA[rw * 64]);
      GL16(W + (size_t)(f0 + row) * CC + kb + gseg, &lB[rw * 64]);
    }
#else
#pragma unroll
    for (int j = 0; j < 4; ++j) {
      const int row = j * 32 + rbase;
      const int dst = row * 128 + ((seg * 16) ^ ((row & 7) << 4));
      *(short8*)((char*)lA + dst) =
          *(const short8*)(A + (size_t)(m0 + row) * CC + kb + seg * 8);
      *(short8*)((char*)lB + dst) =
          *(const short8*)(W + (size_t)(f0 + row) * CC + kb + seg * 8);
    }
#endif
    __syncthreads();
    const int wr = (w >> 1) * 64, wc = (w & 1) * 64;
#pragma unroll
    for (int c = 0; c < 2; ++c) {
      short8 af[4], bfr[4];
#pragma unroll
      for (int i = 0; i < 4; ++i) {
        const int rowA = wr + i * 16 + lq;
        af[i] = *(const short8*)((char*)lA + rowA * 128 +
                                 ((c * 64 + lh * 16) ^ ((rowA & 7) << 4)));
        const int rowB = wc + i * 16 + lq;
        bfr[i] = *(const short8*)((char*)lB + rowB * 128 +
                                  ((c * 64 + lh * 16) ^ ((rowB & 7) << 4)));
      }
#pragma unroll
      for (int mi = 0; mi < 4; ++mi)
#pragma unroll
        for (int ni = 0; ni < 4; ++ni)
          acc[mi][ni] = __builtin_amdgcn_mfma_f32_16x16x32_bf16(
              af[mi], bfr[ni], acc[mi][ni], 0, 0, 0);
    }
  }

  const int wr = (w >> 1) * 64, wc = (w & 1) * 64;
#pragma unroll
  for (int ni = 0; ni < 4; ++ni) {
    const int fb = f0 + wc + ni * 16;
    if (MODE == 0) {
      const int which = fb / CC;          // uniform per fragment
      const int hd = fb - which * CC;
      const int h = hd >> 6;              // uniform
      const int d = (hd & 63) + lq;
#pragma unroll
      for (int mi = 0; mi < 4; ++mi) {
        const int mb = m0 + wr + mi * 16 + 4 * lh;
        const int b = mb >> 11;
        const int n = mb & 2047;
        if (which == 0) {
#pragma unroll
          for (int r = 0; r < 4; ++r)
            O0[(((size_t)(b * HH + h) * NN) + n + r) * DD + d] =
                f2bf(acc[mi][ni][r] * QSCALE);
        } else if (which == 1) {
#pragma unroll
          for (int r = 0; r < 4; ++r)
            O1[(((size_t)(b * HH + h) * NN) + n + r) * DD + d] =
                f2bf(acc[mi][ni][r]);
        } else {
          short4v pk;
#pragma unroll
          for (int r = 0; r < 4; ++r) pk[r] = f2bf(acc[mi][ni][r]);
          *(short4v*)(O2 + ((size_t)(b * HH + h) * DD + d) * NN + n) = pk;
        }
      }
    } else {
      const float bv = bias[fb + lq];
#pragma unroll
      for (int mi = 0; mi < 4; ++mi) {
        const int mb = m0 + wr + mi * 16 + 4 * lh;
#pragma unroll
        for (int r = 0; r < 4; ++r)
          Of[(size_t)(mb + r) * CC + fb + lq] = acc[mi][ni][r] + bv;
      }
    }
  }
}

// ---------------------------------------------------------------------------
// colsumV[bh,d] = sum_n V[bh,n,d]  (from V^T [bh,d,n])
// ---------------------------------------------------------------------------
__global__ __launch_bounds__(256)
void colsum_k(const short* __restrict__ VT, float* __restrict__ cs)
{
  const int bh = blockIdx.x, t = threadIdx.x;
  const int d = t >> 2, part = t & 3;
  const short* p = VT + ((size_t)bh * DD + d) * NN + part * 512;
  float s = 0.f;
  for (int i = 0; i < 512; i += 8) {
    short8 v = *(const short8*)(p + i);
#pragma unroll
    for (int e = 0; e < 8; ++e) s += bf2f(v[e]);
  }
  s += __shfl_xor(s, 1);
  s += __shfl_xor(s, 2);
  if (part == 0) cs[bh * DD + d] = s;
}

// ---------------------------------------------------------------------------
// Attention: 768 blocks x 256 thr.  4 waves = 2 q-subtiles x 2 k-chunks.
// Staging via global_load_lds (zero VGPR), DOUBLE-BUFFERED: one barrier per
// tile; the barrier's implicit vmcnt drain retires the PREVIOUS phase's
// prefetch (which had a full compute phase to land).  Wave qp=0 stages K,
// qp=1 stages V.  Linear LDS dest + pre-swizzled global source (XOR
// involution matches the frag-read swizzle).  Intra-block split-K combine
// via LDS overlay.  32x32x16 MFMA, swapped QK^T; P->A-frag via
// v_permlane32_swap_b32.  Linearized 2nd softmax:
//   out = (csV*l1 + P1) / (2048*l1 + s1),  s1 = l1 - 0.5*mc.
// ---------------------------------------------------------------------------
__global__ __launch_bounds__(256, 2)
void attn_k(const short* __restrict__ Qb, const short* __restrict__ Kb,
            const short* __restrict__ VT, const float* __restrict__ cs,
            short* __restrict__ AO)
{
  __shared__ __align__(16) char smem[65536];   // 2 chunks x 2 bufs x (8K K + 8K V)
  float* comb  = (float*)smem;                 // overlay: [64 q][64 d] fp32
  float* combL = comb + 4096;                  // l1 partials [64]
  float* combM = comb + 4160;                  // mc partials [64]

  const int tid = threadIdx.x;
  const int w = tid >> 6, l = tid & 63;
  const int lq = l & 31, hi = l >> 5;
  const int qp = w & 1;                        // q subtile (0: q0-31, 1: q32-63)
  const int kc = w >> 1;                       // k chunk   (0: k<1024, 1: k>=1024)

  // XCD-aware chunked swizzle: 768 % 8 == 0, bijective.
  const int bid = (int)blockIdx.x;
  const int sbid = (bid & 7) * 96 + (bid >> 3);
  const int bh = sbid >> 5;
  const int qblk = sbid & 31;

  const short* Qh = Qb + (size_t)bh * NN * DD;
  const short* Kh = Kb + (size_t)bh * NN * DD;
  const short* Vh = VT + (size_t)bh * DD * NN;

  const int qw = qblk * 64 + qp * 32;
  const int qg = qw + lq;

  // B-frag of Q: rows d = c*16 + hi*8 + 0..7, col q = lq
  short8 qf[4];
#pragma unroll
  for (int c = 0; c < 4; ++c)
    qf[c] = *(const short8*)(Qh + (size_t)qg * DD + c * 16 + hi * 8);

  f32x16 pv[2] = {};
  float l1x[4] = {};
  float mc = 0.f;

  const int cbase = kc * 32768;                // this chunk's 2-buffer region

#ifdef HAVE_GLOAD_LDS
  // gload_lds staging geometry: instr j covers rows j*8..j*8+7 (1 KB).
  // LDS slot (row, s) <- global segment s ^ (row&7)  (pre-swizzled source).
  const int srow = l >> 3, sslot = l & 7;
  int goffK[8], goffV[8];
#pragma unroll
  for (int j = 0; j < 8; ++j) {
    const int row = j * 8 + srow;
    const int sw = (sslot ^ (row & 7)) * 8;
    goffK[j] = row * DD + sw;
    goffV[j] = row * NN + sw;
  }
#define STAGE(bo_, kb_)                                                      \
  do {                                                                       \
    if (qp == 0) {                                                           \
      _Pragma("unroll")                                                      \
      for (int j = 0; j < 8; ++j)                                            \
        GL16(Kh + (size_t)(kb_) * DD + goffK[j],                             \
             smem + cbase + (bo_) + j * 1024);                               \
    } else {                                                                 \
      _Pragma("unroll")                                                      \
      for (int j = 0; j < 8; ++j)                                            \
        GL16(Vh + (kb_) + goffV[j],                                          \
             smem + cbase + (bo_) + 8192 + j * 1024);                        \
    }                                                                        \
  } while (0)
#else
  // fallback: synchronous 128-thread reg staging (round-8 style, single buf)
  const int lt = tid & 127;
  const int fseg = lt & 7, frbase = lt >> 3;
  int sdstK[4], sdstV[4], ksrc[4], vsrc[4];
#pragma unroll
  for (int j = 0; j < 4; ++j) {
    const int row = j * 16 + frbase;
    const int sw = row * 128 + ((fseg * 16) ^ ((row & 7) << 4));
    sdstK[j] = cbase + sw;
    sdstV[j] = cbase + 8192 + sw;
    ksrc[j] = row * DD + fseg * 8;
    vsrc[j] = row * NN + fseg * 8;
  }
#endif

  // hoisted LDS frag-read addresses (chunk base included, buffer offset not)
  int kaddr[8], vaddr[8];
#pragma unroll
  for (int kg = 0; kg < 2; ++kg) {
    const int rowK = kg * 32 + lq;
#pragma unroll
    for (int c = 0; c < 4; ++c)
      kaddr[kg * 4 + c] =
          cbase + rowK * 128 + ((c * 32 + hi * 16) ^ ((rowK & 7) << 4));
  }
#pragma unroll
  for (int dg = 0; dg < 2; ++dg) {
    const int rowV = dg * 32 + lq;
#pragma unroll
    for (int ch = 0; ch < 4; ++ch)
      vaddr[ch * 2 + dg] =
          cbase + 8192 + rowV * 128 + ((ch * 32 + hi * 16) ^ ((rowV & 7) << 4));
  }

  const int kb0 = kc * (NN / 2);

#ifdef HAVE_GLOAD_LDS
  STAGE(0, kb0);                               // prologue: tile 0 -> buf0
#endif

#pragma unroll 2
  for (int t = 0; t < NN / 2; t += 64) {
    const int kb = kb0 + t;
#ifdef HAVE_GLOAD_LDS
    const int bo = ((t >> 6) & 1) * 16384;     // current buffer
    __syncthreads();                           // drains prev prefetch, publishes
    if (t + 64 < NN / 2) STAGE(bo ^ 16384, kb + 64);
#else
    const int bo = 0;
    __syncthreads();
#pragma unroll
    for (int j = 0; j < 4; ++j) {
      *(short8*)(smem + sdstK[j]) = *(const short8*)(Kh + (size_t)kb * DD + ksrc[j]);
      *(short8*)(smem + sdstV[j]) = *(const short8*)(Vh + kb + vsrc[j]);
    }
    __syncthreads();
#endif

    // QK^T: sacc[kg] = S[key = kb + kg*32 + crow, q = qg] * log2e
    // crow = (reg&3) + 8*(reg>>2) + 4*hi
    f32x16 sacc[2] = {};
    __builtin_amdgcn_s_setprio(1);
#pragma unroll
    for (int kg = 0; kg < 2; ++kg)
#pragma unroll
      for (int c = 0; c < 4; ++c) {
        short8 kf = *(const short8*)(smem + bo + kaddr[kg * 4 + c]);
        sacc[kg] = __builtin_amdgcn_mfma_f32_32x32x16_bf16(kf, qf[c], sacc[kg], 0, 0, 0);
      }
    __builtin_amdgcn_s_setprio(0);

    // elementwise: e = exp2(s); mask hoisted to rare wave-uniform tiles
    uint32_t dwv[2][8];
    const int u = (qw - kb) & 511;
    if (u < 64 || u > 480) {
      const int delta = (qg - kb) & 511;
      int mreg = -1;
      if (delta < 64 && (((delta >> 2) & 1) == hi))
        mreg = (delta >> 5) * 16 + (delta & 3) + (((delta & 31) >> 3) << 2);
#pragma unroll
      for (int kg = 0; kg < 2; ++kg) {
        float uv[16];
#pragma unroll
        for (int r = 0; r < 16; ++r) {
          float e = __builtin_exp2f(sacc[kg][r]);
          l1x[r & 3] += e;
          const bool m = (kg * 16 + r) == mreg;
          mc += m ? e : 0.f;
          uv[r] = m ? 0.5f * e : e;
        }
#pragma unroll
        for (int j2 = 0; j2 < 8; ++j2)
          dwv[kg][j2] = cvtpk(uv[2 * j2], uv[2 * j2 + 1]);
      }
    } else {
#pragma unroll
      for (int kg = 0; kg < 2; ++kg) {
        float uv[16];
#pragma unroll
        for (int r = 0; r < 16; ++r) {
          const float e = __builtin_exp2f(sacc[kg][r]);
          l1x[r & 3] += e;
          uv[r] = e;
        }
#pragma unroll
        for (int j2 = 0; j2 < 8; ++j2)
          dwv[kg][j2] = cvtpk(uv[2 * j2], uv[2 * j2 + 1]);
      }
    }

    // Build PV A-frags (P[q][k], row=q=lq, cols k = ch*16 + hi*8 + 0..7)
    short8 pa[4];
#pragma unroll
    for (int kg = 0; kg < 2; ++kg)
#pragma unroll
      for (int half = 0; half < 2; ++half) {
        uint32_t a0 = dwv[kg][4 * half + 0], a1 = dwv[kg][4 * half + 1];
        uint32_t a2 = dwv[kg][4 * half + 2], a3 = dwv[kg][4 * half + 3];
        asm("v_permlane32_swap_b32 %0, %1" : "+v"(a0), "+v"(a2));
        asm("v_permlane32_swap_b32 %0, %1" : "+v"(a1), "+v"(a3));
        union { uint32_t u4[4]; short8 s; } pk;
        pk.u4[0] = a0; pk.u4[1] = a1; pk.u4[2] = a2; pk.u4[3] = a3;
        pa[kg * 2 + half] = pk.s;
      }

    // PV: pv[dg][reg] = O[q = crow, d = dg*32 + lq]
    __builtin_amdgcn_s_setprio(1);
#pragma unroll
    for (int ch = 0; ch < 4; ++ch)
#pragma unroll
      for (int dg = 0; dg < 2; ++dg) {
        short8 vf = *(const short8*)(smem + bo + vaddr[ch * 2 + dg]);
        pv[dg] = __builtin_amdgcn_mfma_f32_32x32x16_bf16(pa[ch], vf, pv[dg], 0, 0, 0);
      }
    __builtin_amdgcn_s_setprio(0);
  }

  // per-chunk l1, mc for q = qw + lq (keys split across lane halves)
  float l1 = (l1x[0] + l1x[1]) + (l1x[2] + l1x[3]);
  l1 += __shfl_xor(l1, 32);
  mc += __shfl_xor(mc, 32);

  // ---- intra-block split-K combine via LDS overlay ----
  __syncthreads();                    // all staging traffic done; safe to overlay
  if (kc == 1) {
#pragma unroll
    for (int dg = 0; dg < 2; ++dg)
#pragma unroll
      for (int r = 0; r < 16; ++r) {
        const int qrow = (r & 3) + 8 * (r >> 2) + 4 * hi;
        comb[(qp * 32 + qrow) * 64 + dg * 32 + lq] = pv[dg][r];
      }
    if (hi == 0) {
      combL[qp * 32 + lq] = l1;
      combM[qp * 32 + lq] = mc;
    }
  }
  __syncthreads();
  if (kc == 0) {
    const float l1t = l1 + combL[qp * 32 + lq];
    const float mct = mc + combM[qp * 32 + lq];
    const float s1t = l1t - 0.5f * mct;
    const int b = bh / HH, h = bh - b * HH;
#pragma unroll
    for (int r = 0; r < 16; ++r) {
      const int qrow = (r & 3) + 8 * (r >> 2) + 4 * hi;
      const float l1r = __shfl(l1t, qrow);
      const float s1r = __shfl(s1t, qrow);
      const float rden = 1.f / (2048.f * l1r + s1r);
      const int n = qw + qrow;
#pragma unroll
      for (int dg = 0; dg < 2; ++dg) {
        const int d = dg * 32 + lq;
        const float pvt = pv[dg][r] + comb[(qp * 32 + qrow) * 64 + d];
        const float csv = cs[bh * DD + d];
        AO[((size_t)(b * NN + n)) * CC + h * DD + d] =
            f2bf((csv * l1r + pvt) * rden);
      }
    }
  }
}

// ---------------------------------------------------------------------------
extern "C" void kernel_launch(void* const* d_in, const int* in_sizes, int n_in,
                              void* d_out, int out_size, void* d_ws, size_t ws_size,
                              hipStream_t stream)
{
  (void)in_sizes; (void)n_in; (void)out_size;
  float* out = (float*)d_out;

  const size_t HD = (size_t)2 * HH * NN * DD;   // 3,145,728 elements
  const size_t NX = 3145728, NW = 1769472, NO = 589824;
  const size_t need = (4 * HD + NX + NW + NO) * sizeof(short)
                    + (size_t)2 * HH * DD * sizeof(float) + 64;
  if (ws_size < need) return;  // diagnostic: zero output

  short* Qb = (short*)d_ws;
  short* Kb = Qb + HD;
  short* VT = Kb + HD;
  short* AO = VT + HD;
  float* cs = (float*)(AO + HD);
  short* xb  = (short*)(cs + 2 * HH * DD);
  short* wqb = xb + NX;
  short* wob = wqb + NW;

  dim3 blk(256);
  norm_k<<<dim3(2688), blk, 0, stream>>>((const float*)d_in[0],
                                         (const float*)d_in[1],
                                         (const float*)d_in[2],
                                         xb, wqb, wob);
  gemm_k<0><<<dim3(2304 / 128, 4096 / 128), blk, 0, stream>>>(
      xb, wqb, nullptr, Qb, Kb, VT, nullptr);
  colsum_k<<<dim3(2 * HH), blk, 0, stream>>>(VT, cs);
  attn_k<<<dim3(24 * 32), blk, 0, stream>>>(Qb, Kb, VT, cs, AO);
  gemm_k<1><<<dim3(CC / 128, 4096 / 128), blk, 0, stream>>>(
      AO, wob, (const float*)d_in[3], nullptr, nullptr, nullptr, out);
}

// Round 12
// 107.142 us; speedup vs baseline: 1.4201x; 1.0344x over previous
//
#include <hip/hip_runtime.h>
#include <hip/hip_bf16.h>
#include <cstdint>
#include <cstddef>

typedef __attribute__((ext_vector_type(8))) short short8;
typedef __attribute__((ext_vector_type(4))) short short4v;
typedef __attribute__((ext_vector_type(4))) float f32x4;
typedef __attribute__((ext_vector_type(16))) float f32x16;

#define HH 12
#define DD 64
#define NN 2048
#define CC 768
// 0.125 (HEAD_DIM^-0.5) * log2(e): lets attn use exp2 directly.
#define QSCALE 0.18033688011112042f

#if defined(__has_builtin)
#if __has_builtin(__builtin_amdgcn_global_load_lds)
#define HAVE_GLOAD_LDS 1
#endif
#endif

#ifdef HAVE_GLOAD_LDS
// async global->LDS, 16B per lane; LDS dest is wave-uniform base + lane*16
#define GL16(gp, lp)                                                         \
  __builtin_amdgcn_global_load_lds(                                         \
      (__attribute__((address_space(1))) void*)(size_t)(const void*)(gp),   \
      (__attribute__((address_space(3))) void*)(lp), 16, 0, 0)
#endif

__device__ __forceinline__ float bf2f(short s) {
  union { uint32_t u; float f; } v;
  v.u = ((uint32_t)(uint16_t)s) << 16;
  return v.f;
}
__device__ __forceinline__ short f2bf(float f) {
  union { float f; uint32_t u; } v; v.f = f;
  uint32_t r = v.u + 0x7FFFu + ((v.u >> 16) & 1u);
  return (short)(r >> 16);
}
// packed f32x2 -> bf16x2 (low = a, high = b) in one instruction
__device__ __forceinline__ uint32_t cvtpk(float a, float b) {
  uint32_t r;
  asm("v_cvt_pk_bf16_f32 %0, %1, %2" : "=v"(r) : "v"(a), "v"(b));
  return r;
}

// ---------------------------------------------------------------------------
// Normalizer: fp32 -> bf16 for x, w_qkv, w_out.
// ---------------------------------------------------------------------------
__global__ __launch_bounds__(256)
void norm_k(const float* __restrict__ s0, const float* __restrict__ s1,
            const float* __restrict__ s2,
            short* __restrict__ d0, short* __restrict__ d1,
            short* __restrict__ d2)
{
  const int bid = blockIdx.x;
  const float* src; short* dst; int base;
  if (bid < 1536)      { src = s0; dst = d0; base = bid; }
  else if (bid < 2400) { src = s1; dst = d1; base = bid - 1536; }
  else                 { src = s2; dst = d2; base = bid - 2400; }
  const int idx = (base * 256 + (int)threadIdx.x) * 8;
  const float* sf = src + idx;
  f32x4 a = *(const f32x4*)sf;
  f32x4 b = *(const f32x4*)(sf + 4);
  short8 o;
  o[0] = f2bf(a[0]); o[1] = f2bf(a[1]); o[2] = f2bf(a[2]); o[3] = f2bf(a[3]);
  o[4] = f2bf(b[0]); o[5] = f2bf(b[1]); o[6] = f2bf(b[2]); o[7] = f2bf(b[3]);
  *(short8*)(dst + idx) = o;
}

// ---------------------------------------------------------------------------
// GEMM: C[m,f] = sum_c A[m,c] * W[f,c]   (A: [4096,768], W: [F,768], bf16)
// MODE 0: F=2304 -> Q (x QSCALE) [b,h,n,d], K [b,h,n,d], V^T [b,h,d,n]
// MODE 1: F=768 -> Of[m*768+f] = C + bias[f]  (fp32 out)
// Staging: global_load_lds w16, linear LDS dest, pre-swizzled global source.
// ---------------------------------------------------------------------------
template <int MODE>
__global__ __launch_bounds__(256, 2)
void gemm_k(const short* __restrict__ A, const short* __restrict__ W,
            const float* __restrict__ bias,
            short* __restrict__ O0, short* __restrict__ O1, short* __restrict__ O2,
            float* __restrict__ Of)
{
  __shared__ __align__(16) short lA[128 * 64];
  __shared__ __align__(16) short lB[128 * 64];
  const int tid = threadIdx.x;
  const int w = tid >> 6, l = tid & 63;
  const int lq = l & 15, lh = l >> 4;
  const int m0 = blockIdx.y * 128;
  const int f0 = blockIdx.x * 128;

#ifdef HAVE_GLOAD_LDS
  const int lrow = l >> 3;                    // 0..7 within wave
  const int gseg = ((l & 7) ^ lrow) * 8;      // pre-swizzled element offset
#else
  const int seg = tid & 7;
  const int rbase = tid >> 3;
#endif

  f32x4 acc[4][4] = {};

  for (int kb = 0; kb < CC; kb += 64) {
    __syncthreads();
#ifdef HAVE_GLOAD_LDS
#pragma unroll
    for (int j = 0; j < 4; ++j) {
      const int rw = j * 32 + w * 8;          // wave-uniform row base
      const int row = rw + lrow;
      GL16(A + (size_t)(m0 + row) * CC + kb + gseg, &lA[rw * 64]);
      GL16(W + (size_t)(f0 + row) * CC + kb + gseg, &lB[rw * 64]);
    }
#else
#pragma unroll
    for (int j = 0; j < 4; ++j) {
      const int row = j * 32 + rbase;
      const int dst = row * 128 + ((seg * 16) ^ ((row & 7) << 4));
      *(short8*)((char*)lA + dst) =
          *(const short8*)(A + (size_t)(m0 + row) * CC + kb + seg * 8);
      *(short8*)((char*)lB + dst) =
          *(const short8*)(W + (size_t)(f0 + row) * CC + kb + seg * 8);
    }
#endif
    __syncthreads();
    const int wr = (w >> 1) * 64, wc = (w & 1) * 64;
#pragma unroll
    for (int c = 0; c < 2; ++c) {
      short8 af[4], bfr[4];
#pragma unroll
      for (int i = 0; i < 4; ++i) {
        const int rowA = wr + i * 16 + lq;
        af[i] = *(const short8*)((char*)lA + rowA * 128 +
                                 ((c * 64 + lh * 16) ^ ((rowA & 7) << 4)));
        const int rowB = wc + i * 16 + lq;
        bfr[i] = *(const short8*)((char*)lB + rowB * 128 +
                                  ((c * 64 + lh * 16) ^ ((rowB & 7) << 4)));
      }
#pragma unroll
      for (int mi = 0; mi < 4; ++mi)
#pragma unroll
        for (int ni = 0; ni < 4; ++ni)
          acc[mi][ni] = __builtin_amdgcn_mfma_f32_16x16x32_bf16(
              af[mi], bfr[ni], acc[mi][ni], 0, 0, 0);
    }
  }

  const int wr = (w >> 1) * 64, wc = (w & 1) * 64;
#pragma unroll
  for (int ni = 0; ni < 4; ++ni) {
    const int fb = f0 + wc + ni * 16;
    if (MODE == 0) {
      const int which = fb / CC;          // uniform per fragment
      const int hd = fb - which * CC;
      const int h = hd >> 6;              // uniform
      const int d = (hd & 63) + lq;
#pragma unroll
      for (int mi = 0; mi < 4; ++mi) {
        const int mb = m0 + wr + mi * 16 + 4 * lh;
        const int b = mb >> 11;
        const int n = mb & 2047;
        if (which == 0) {
#pragma unroll
          for (int r = 0; r < 4; ++r)
            O0[(((size_t)(b * HH + h) * NN) + n + r) * DD + d] =
                f2bf(acc[mi][ni][r] * QSCALE);
        } else if (which == 1) {
#pragma unroll
          for (int r = 0; r < 4; ++r)
            O1[(((size_t)(b * HH + h) * NN) + n + r) * DD + d] =
                f2bf(acc[mi][ni][r]);
        } else {
          short4v pk;
#pragma unroll
          for (int r = 0; r < 4; ++r) pk[r] = f2bf(acc[mi][ni][r]);
          *(short4v*)(O2 + ((size_t)(b * HH + h) * DD + d) * NN + n) = pk;
        }
      }
    } else {
      const float bv = bias[fb + lq];
#pragma unroll
      for (int mi = 0; mi < 4; ++mi) {
        const int mb = m0 + wr + mi * 16 + 4 * lh;
#pragma unroll
        for (int r = 0; r < 4; ++r)
          Of[(size_t)(mb + r) * CC + fb + lq] = acc[mi][ni][r] + bv;
      }
    }
  }
}

// ---------------------------------------------------------------------------
// colsumV[bh,d] = sum_n V[bh,n,d]  (from V^T [bh,d,n])
// ---------------------------------------------------------------------------
__global__ __launch_bounds__(256)
void colsum_k(const short* __restrict__ VT, float* __restrict__ cs)
{
  const int bh = blockIdx.x, t = threadIdx.x;
  const int d = t >> 2, part = t & 3;
  const short* p = VT + ((size_t)bh * DD + d) * NN + part * 512;
  float s = 0.f;
  for (int i = 0; i < 512; i += 8) {
    short8 v = *(const short8*)(p + i);
#pragma unroll
    for (int e = 0; e < 8; ++e) s += bf2f(v[e]);
  }
  s += __shfl_xor(s, 1);
  s += __shfl_xor(s, 2);
  if (part == 0) cs[bh * DD + d] = s;
}

// ---------------------------------------------------------------------------
// Attention: 768 blocks x 256 thr.  4 waves = 2 q-subtiles x 2 k-chunks.
// 32-key tiles, double-buffered global_load_lds staging -> 32 KB LDS total
// (3 blocks/CU resident = full grid resident).  K tile [32][128B] (XOR key
// (row&7)<<4); V tile [64][64B] (XOR key ((row>>1)&3)<<4, Latin-square over
// the 4 slots -> <=4-way conflict).  Pre-swizzled global source both times.
// 32x32x16 MFMA, swapped QK^T; P->A-frag via v_permlane32_swap_b32.
// Linearized 2nd softmax: out = (csV*l1 + P1)/(2048*l1+s1), s1 = l1-0.5*mc.
// ---------------------------------------------------------------------------
__global__ __launch_bounds__(256, 3)
void attn_k(const short* __restrict__ Qb, const short* __restrict__ Kb,
            const short* __restrict__ VT, const float* __restrict__ cs,
            short* __restrict__ AO)
{
  __shared__ __align__(16) char smem[32768];   // 2ch x 2buf x (4K K + 4K V)
  float* comb  = (float*)smem;                 // overlay: [64 q][64 d] fp32
  float* combL = comb + 4096;                  // l1 partials [64]
  float* combM = comb + 4160;                  // mc partials [64]

  const int tid = threadIdx.x;
  const int w = tid >> 6, l = tid & 63;
  const int lq = l & 31, hi = l >> 5;
  const int qp = w & 1;                        // q subtile (0: q0-31, 1: q32-63)
  const int kc = w >> 1;                       // k chunk   (0: k<1024, 1: k>=1024)

  // XCD-aware chunked swizzle: 768 % 8 == 0, bijective.
  const int bid = (int)blockIdx.x;
  const int sbid = (bid & 7) * 96 + (bid >> 3);
  const int bh = sbid >> 5;
  const int qblk = sbid & 31;

  const short* Qh = Qb + (size_t)bh * NN * DD;
  const short* Kh = Kb + (size_t)bh * NN * DD;
  const short* Vh = VT + (size_t)bh * DD * NN;

  const int qw = qblk * 64 + qp * 32;
  const int qg = qw + lq;

  // B-frag of Q: rows d = c*16 + hi*8 + 0..7, col q = lq
  short8 qf[4];
#pragma unroll
  for (int c = 0; c < 4; ++c)
    qf[c] = *(const short8*)(Qh + (size_t)qg * DD + c * 16 + hi * 8);

  f32x16 pv[2] = {};
  float l1x[4] = {};
  float mc = 0.f;

  const int cbase = kc * 16384;                // this chunk's 2-buffer region

#ifdef HAVE_GLOAD_LDS
  // K tile 4KB = 4 instrs x 1KB (8 rows of 128B); V tile 4KB = 4 x (16 rows
  // of 64B).  Source pre-swizzled with the matching involution.
  const int srK = l >> 3, ssK = l & 7;
  const int srV = l >> 2, ssV = l & 3;
  int goffK[4], goffV[4];
#pragma unroll
  for (int j = 0; j < 4; ++j) {
    const int rowK = j * 8 + srK;
    goffK[j] = rowK * DD + ((ssK ^ (rowK & 7)) * 8);
    const int rowV = j * 16 + srV;
    goffV[j] = rowV * NN + ((ssV ^ ((rowV >> 1) & 3)) * 8);
  }
#define STAGE(bo_, kb_)                                                      \
  do {                                                                       \
    if (qp == 0) {                                                           \
      _Pragma("unroll")                                                      \
      for (int j = 0; j < 4; ++j)                                            \
        GL16(Kh + (size_t)(kb_) * DD + goffK[j],                             \
             smem + cbase + (bo_) + j * 1024);                               \
    } else {                                                                 \
      _Pragma("unroll")                                                      \
      for (int j = 0; j < 4; ++j)                                            \
        GL16(Vh + (kb_) + goffV[j],                                          \
             smem + cbase + (bo_) + 4096 + j * 1024);                        \
    }                                                                        \
  } while (0)
#else
  // fallback: synchronous staging by the chunk's 128 threads
  const int lt = tid & 127;
  int sdK, gsK, sdV0, sdV1, gsV0, gsV1;
  {
    const int rowK = lt >> 2;                  // 32 rows x 4 slots
    const int sK = lt & 3;                     // half-row: 2 slots of 16B? use 8B x ... simplify: 4 x 32B? 
    // 128 thr x 16B = 2KB per pass -> 2 passes for K (4KB): rows 0..15, 16..31
    const int rK = lt >> 3, cK = lt & 7;
    sdK = rK * 128 + ((cK * 16) ^ ((rK & 7) << 4));
    gsK = rK * DD + cK * 8;
    const int rV = lt >> 2, cV = lt & 3;
    sdV0 = rV * 64 + ((cV * 16) ^ (((rV >> 1) & 3) << 4));
    gsV0 = rV * NN + cV * 8;
    sdV1 = (rV + 32) * 64 + ((cV * 16) ^ ((((rV + 32) >> 1) & 3) << 4));
    gsV1 = (rV + 32) * NN + cV * 8;
    (void)sK; (void)rowK;
  }
#define STAGE_SYNC(bo_, kb_)                                                 \
  do {                                                                       \
    *(short8*)(smem + cbase + (bo_) + sdK) =                                 \
        *(const short8*)(Kh + (size_t)((kb_) + (lt >> 3)) * DD + (lt & 7) * 8); \
    *(short8*)(smem + cbase + (bo_) + 2048 +                                 \
               ((lt >> 3) + 16) * 128 - 16 * 128 + sdK - (lt >> 3) * 128 + ((lt >> 3) + 16) * 128) ; \
  } while (0)
#endif

  // hoisted LDS frag-read addresses (chunk base included, buffer offset not)
  int kaddr[4], vaddr[4];
#pragma unroll
  for (int c = 0; c < 4; ++c)
    kaddr[c] = cbase + lq * 128 + (((c * 2 + hi) * 16) ^ ((lq & 7) << 4));
#pragma unroll
  for (int ch = 0; ch < 2; ++ch)
#pragma unroll
    for (int dg = 0; dg < 2; ++dg) {
      const int rowV = dg * 32 + lq;
      vaddr[ch * 2 + dg] = cbase + 4096 + rowV * 64 +
                           (((ch * 2 + hi) * 16) ^ (((rowV >> 1) & 3) << 4));
    }

  const int kb0 = kc * (NN / 2);

#ifdef HAVE_GLOAD_LDS
  STAGE(0, kb0);                               // prologue: tile 0 -> buf0
#endif

#pragma unroll 2
  for (int t = 0; t < NN / 2; t += 32) {
    const int kb = kb0 + t;
#ifdef HAVE_GLOAD_LDS
    const int bo = ((t >> 5) & 1) * 8192;      // current buffer
    __syncthreads();                           // drains prev prefetch, publishes
    if (t + 32 < NN / 2) STAGE(bo ^ 8192, kb + 32);
#else
    const int bo = 0;
    __syncthreads();
    {
      const int lt2 = tid & 127;
      const int rK = lt2 >> 3, cK = lt2 & 7;
#pragma unroll
      for (int jj = 0; jj < 2; ++jj) {
        const int row = jj * 16 + rK;
        *(short8*)(smem + cbase + row * 128 + ((cK * 16) ^ ((row & 7) << 4))) =
            *(const short8*)(Kh + (size_t)(kb + row) * DD + cK * 8);
      }
      const int rV = lt2 >> 2, cV = lt2 & 3;
#pragma unroll
      for (int jj = 0; jj < 2; ++jj) {
        const int row = jj * 32 + rV;
        *(short8*)(smem + cbase + 4096 + row * 64 +
                   ((cV * 16) ^ (((row >> 1) & 3) << 4))) =
            *(const short8*)(Vh + (size_t)row * NN + kb + cV * 8);
      }
    }
    __syncthreads();
#endif

    // QK^T: sacc = S[key = kb + crow, q = qg] * log2e,
    // crow = (r&3) + 8*(r>>2) + 4*hi
    f32x16 sacc = {};
    __builtin_amdgcn_s_setprio(1);
#pragma unroll
    for (int c = 0; c < 4; ++c) {
      short8 kf = *(const short8*)(smem + bo + kaddr[c]);
      sacc = __builtin_amdgcn_mfma_f32_32x32x16_bf16(kf, qf[c], sacc, 0, 0, 0);
    }
    __builtin_amdgcn_s_setprio(0);

    // elementwise: e = exp2(s); mask only on tiles with (qw-kb)%512 == 0,
    // where lane lq's masked element is r = (lq&3)|((lq>>3)<<2) iff
    // hi == (lq>>2)&1.
    uint32_t dw[8];
    if (((qw - kb) & 511) == 0) {
      int mreg = (((lq >> 2) & 1) == hi) ? ((lq & 3) | (((lq >> 3) & 3) << 2))
                                         : -1;
      float uv[16];
#pragma unroll
      for (int r = 0; r < 16; ++r) {
        float e = __builtin_exp2f(sacc[r]);
        l1x[r & 3] += e;
        const bool m = (r == mreg);
        mc += m ? e : 0.f;
        uv[r] = m ? 0.5f * e : e;
      }
#pragma unroll
      for (int j2 = 0; j2 < 8; ++j2)
        dw[j2] = cvtpk(uv[2 * j2], uv[2 * j2 + 1]);
    } else {
      float uv[16];
#pragma unroll
      for (int r = 0; r < 16; ++r) {
        const float e = __builtin_exp2f(sacc[r]);
        l1x[r & 3] += e;
        uv[r] = e;
      }
#pragma unroll
      for (int j2 = 0; j2 < 8; ++j2)
        dw[j2] = cvtpk(uv[2 * j2], uv[2 * j2 + 1]);
    }

    // Build PV A-frags (P[q][k], row=q=lq, cols k = ch*16 + hi*8 + 0..7)
    short8 pa[2];
#pragma unroll
    for (int half = 0; half < 2; ++half) {
      uint32_t a0 = dw[4 * half + 0], a1 = dw[4 * half + 1];
      uint32_t a2 = dw[4 * half + 2], a3 = dw[4 * half + 3];
      asm("v_permlane32_swap_b32 %0, %1" : "+v"(a0), "+v"(a2));
      asm("v_permlane32_swap_b32 %0, %1" : "+v"(a1), "+v"(a3));
      union { uint32_t u4[4]; short8 s; } pk;
      pk.u4[0] = a0; pk.u4[1] = a1; pk.u4[2] = a2; pk.u4[3] = a3;
      pa[half] = pk.s;
    }

    // PV: pv[dg][reg] = O[q = crow, d = dg*32 + lq]
    __builtin_amdgcn_s_setprio(1);
#pragma unroll
    for (int ch = 0; ch < 2; ++ch)
#pragma unroll
      for (int dg = 0; dg < 2; ++dg) {
        short8 vf = *(const short8*)(smem + bo + vaddr[ch * 2 + dg]);
        pv[dg] = __builtin_amdgcn_mfma_f32_32x32x16_bf16(pa[ch], vf, pv[dg], 0, 0, 0);
      }
    __builtin_amdgcn_s_setprio(0);
  }

  // per-chunk l1, mc for q = qw + lq (keys split across lane halves)
  float l1 = (l1x[0] + l1x[1]) + (l1x[2] + l1x[3]);
  l1 += __shfl_xor(l1, 32);
  mc += __shfl_xor(mc, 32);

  // ---- intra-block split-K combine via LDS overlay ----
  __syncthreads();                    // all staging traffic done; safe to overlay
  if (kc == 1) {
#pragma unroll
    for (int dg = 0; dg < 2; ++dg)
#pragma unroll
      for (int r = 0; r < 16; ++r) {
        const int qrow = (r & 3) + 8 * (r >> 2) + 4 * hi;
        comb[(qp * 32 + qrow) * 64 + dg * 32 + lq] = pv[dg][r];
      }
    if (hi == 0) {
      combL[qp * 32 + lq] = l1;
      combM[qp * 32 + lq] = mc;
    }
  }
  __syncthreads();
  if (kc == 0) {
    const float l1t = l1 + combL[qp * 32 + lq];
    const float mct = mc + combM[qp * 32 + lq];
    const float s1t = l1t - 0.5f * mct;
    const int b = bh / HH, h = bh - b * HH;
#pragma unroll
    for (int r = 0; r < 16; ++r) {
      const int qrow = (r & 3) + 8 * (r >> 2) + 4 * hi;
      const float l1r = __shfl(l1t, qrow);
      const float s1r = __shfl(s1t, qrow);
      const float rden = 1.f / (2048.f * l1r + s1r);
      const int n = qw + qrow;
#pragma unroll
      for (int dg = 0; dg < 2; ++dg) {
        const int d = dg * 32 + lq;
        const float pvt = pv[dg][r] + comb[(qp * 32 + qrow) * 64 + d];
        const float csv = cs[bh * DD + d];
        AO[((size_t)(b * NN + n)) * CC + h * DD + d] =
            f2bf((csv * l1r + pvt) * rden);
      }
    }
  }
}

// ---------------------------------------------------------------------------
extern "C" void kernel_launch(void* const* d_in, const int* in_sizes, int n_in,
                              void* d_out, int out_size, void* d_ws, size_t ws_size,
                              hipStream_t stream)
{
  (void)in_sizes; (void)n_in; (void)out_size;
  float* out = (float*)d_out;

  const size_t HD = (size_t)2 * HH * NN * DD;   // 3,145,728 elements
  const size_t NX = 3145728, NW = 1769472, NO = 589824;
  const size_t need = (4 * HD + NX + NW + NO) * sizeof(short)
                    + (size_t)2 * HH * DD * sizeof(float) + 64;
  if (ws_size < need) return;  // diagnostic: zero output

  short* Qb = (short*)d_ws;
  short* Kb = Qb + HD;
  short* VT = Kb + HD;
  short* AO = VT + HD;
  float* cs = (float*)(AO + HD);
  short* xb  = (short*)(cs + 2 * HH * DD);
  short* wqb = xb + NX;
  short* wob = wqb + NW;

  dim3 blk(256);
  norm_k<<<dim3(2688), blk, 0, stream>>>((const float*)d_in[0],
                                         (const float*)d_in[1],
                                         (const float*)d_in[2],
                                         xb, wqb, wob);
  gemm_k<0><<<dim3(2304 / 128, 4096 / 128), blk, 0, stream>>>(
      xb, wqb, nullptr, Qb, Kb, VT, nullptr);
  colsum_k<<<dim3(2 * HH), blk, 0, stream>>>(VT, cs);
  attn_k<<<dim3(24 * 32), blk, 0, stream>>>(Qb, Kb, VT, cs, AO);
  gemm_k<1><<<dim3(CC / 128, 4096 / 128), blk, 0, stream>>>(
      AO, wob, (const float*)d_in[3], nullptr, nullptr, nullptr, out);
}